// Round 3
// baseline (79.202 us; speedup 1.0000x reference)
//
#include <hip/hip_runtime.h>

// Problem constants: B=2, C=32, H=128, W=256, maxdisp=12 -> D=23, shift = di-11
#define BB 2
#define CC 32
#define HH 128
#define WW 256
#define DD 23
#define HW (HH * WW)

#define SEG 32            // pixels per block (W split 8 ways)
#define NSEG 8
#define NCOLS 119         // staged cols: [32s-75 .. 32s+43]  (32 + 87)
#define SC 36             // col stride in dwords (144 B, 16B-aligned, odd quad)
#define RED 23            // combine stride (23 coprime 32 -> 2-way alias = free)
#define REGION (32 * RED) // 736 floats per wave's partial region
#define SMEMF (NCOLS * SC) // 4284 floats = 17136 B (> 4*REGION = 2944)

// LDS: smem[col*SC + c] = feat_r[b, c, h, col + COL0], zero outside [0,W).
// After compute it is reused as the 4-region cross-wave reduction buffer.
// 17.1 KB/block -> 8 blocks/CU; with VGPR<=64 that is 32 waves/CU (100% occ).

__global__ __launch_bounds__(256, 8) void cost_volume_kernel(
    const float* __restrict__ feat_l,
    const float* __restrict__ feat_r,
    const float* __restrict__ disp,
    float* __restrict__ out)
{
    __shared__ __align__(16) float smem[SMEMF];

    const int t    = threadIdx.x;
    const int lane = t & 63;
    const int px   = t & 31;        // pixel within segment
    const int cg   = t >> 5;        // channel quad 0..7 (c0 = 4*cg)
    const int wv   = t >> 6;        // wave 0..3 (holds cg = 2wv, 2wv+1)
    const int s  = blockIdx.x >> 8; // grid = NSEG*256; siblings same XCD (256%8==0)
    const int bh = blockIdx.x & 255;
    const int b  = bh >> 7;
    const int h  = bh & 127;
    const int w  = s * SEG + px;
    const int COL0 = s * SEG - 75;
    const int c0 = cg * 4;

    // ---- early independent global loads (overlap staging latency) ----
    float fl[4];
    const size_t lbase = ((size_t)(b * CC + c0)) * HW + (size_t)h * WW + w;
    #pragma unroll
    for (int k = 0; k < 4; ++k) fl[k] = feat_l[lbase + (size_t)k * HW];
    const float d = disp[(size_t)bh * WW + w];

    // ---- stage feat_r window, channel-interleaved, b128 LDS writes ----
    // col = t&127 (covers 0..118), half hq = t>>7 stages channel-quads hq*4..hq*4+3
    {
        const int col = t & 127;
        const int hq  = t >> 7;
        if (col < NCOLS) {
            const int  gcol = col + COL0;
            const bool inr  = (gcol >= 0) && (gcol < WW);
            const int  gc   = min(max(gcol, 0), WW - 1);   // safe address
            #pragma unroll
            for (int qq = 0; qq < 4; ++qq) {
                const int cq = (hq * 4 + qq) * 4;          // channel quad base
                const size_t base = ((size_t)(b * CC + cq)) * HW + (size_t)h * WW + gc;
                const float x0 = feat_r[base];
                const float x1 = feat_r[base + HW];
                const float x2 = feat_r[base + 2 * HW];
                const float x3 = feat_r[base + 3 * HW];
                float4 v;
                v.x = inr ? x0 : 0.0f;
                v.y = inr ? x1 : 0.0f;
                v.z = inr ? x2 : 0.0f;
                v.w = inr ? x3 : 0.0f;
                *(float4*)&smem[col * SC + cq] = v;
            }
        }
    }
    __syncthreads();

    // ---- per-pixel interp setup (shared across all di) ----
    const float pxf = (float)w - d;
    const float x0f = floorf(pxf);
    const float w1  = pxf - x0f;          // right-neighbor weight
    const float w0  = 1.0f - w1;
    int lb = (int)x0f - COL0 - 11;        // local col of tap j=0
    lb = min(max(lb, 0), NCOLS - 24);     // no-op for disp in [0,64)

    // ---- 24-tap window, prefetch distance 2, 4 channels per thread ----
    float4 Ta[3];
    #define LOADTAP(idx, j) Ta[idx] = *(const float4*)&smem[(lb + (j)) * SC + c0];

    LOADTAP(0, 0)
    LOADTAP(1, 1)

    float acc[DD];
    #pragma unroll
    for (int di = 0; di < DD; ++di) {
        if (di + 2 < 24) LOADTAP((di + 2) % 3, di + 2)
        const float4 A = Ta[di % 3];
        const float4 B = Ta[(di + 1) % 3];
        const float s0 = fabsf(fmaf(w0, A.x, fmaf(w1, B.x, -fl[0])));
        const float s1 = fabsf(fmaf(w0, A.y, fmaf(w1, B.y, -fl[1])));
        const float s2 = fabsf(fmaf(w0, A.z, fmaf(w1, B.z, -fl[2])));
        const float s3 = fabsf(fmaf(w0, A.w, fmaf(w1, B.w, -fl[3])));
        acc[di] = (s0 + s1) + (s2 + s3);
    }
    #undef LOADTAP

    // ---- pair-combine across lane^32 (same px, neighboring channel quad) ----
    #pragma unroll
    for (int di = 0; di < DD; ++di)
        acc[di] += __shfl_xor(acc[di], 32, 64);

    // ---- cross-wave combine (reuse smem; stride 23 = conflict-free) ----
    __syncthreads();                       // all tap reads done before overwrite
    if (lane < 32) {                       // lanes l, l^32 hold identical sums
        float* r = &smem[wv * REGION + px * RED];
        #pragma unroll
        for (int di = 0; di < DD; ++di) r[di] = acc[di];
    }
    __syncthreads();
    // 32 px * 23 di = 736 outputs over 256 threads, coalesced per-di runs
    #pragma unroll
    for (int k = 0; k < 3; ++k) {
        const int o = t + 256 * k;
        if (o < 32 * DD) {
            const int di2 = o >> 5;
            const int p2  = o & 31;
            const float* r0 = &smem[p2 * RED + di2];
            const float v = (r0[0] + r0[REGION]) + (r0[2 * REGION] + r0[3 * REGION]);
            out[((size_t)(b * DD + di2)) * HW + (size_t)h * WW + (s * SEG + p2)] = v;
        }
    }
}

extern "C" void kernel_launch(void* const* d_in, const int* in_sizes, int n_in,
                              void* d_out, int out_size, void* d_ws, size_t ws_size,
                              hipStream_t stream)
{
    const float* feat_l = (const float*)d_in[0];
    const float* feat_r = (const float*)d_in[1];
    const float* disp   = (const float*)d_in[2];
    float* out = (float*)d_out;

    dim3 grid(NSEG * BB * HH);   // 2048 blocks: (wseg, b, h); 8 blocks/CU
    dim3 block(256);             // 4 waves: (px 0..31) x (channel-quad pair)
    cost_volume_kernel<<<grid, block, 0, stream>>>(feat_l, feat_r, disp, out);
}

// Round 4
// 77.936 us; speedup vs baseline: 1.0162x; 1.0162x over previous
//
#include <hip/hip_runtime.h>

// Problem constants: B=2, C=32, H=128, W=256, maxdisp=12 -> D=23, shift = di-11
#define BB 2
#define CC 32
#define HH 128
#define WW 256
#define DD 23
#define HW (HH * WW)

#define SEG 64            // pixels per block (W split 4 ways)
#define NSEG 4
#define NCOLS 151         // staged cols: [64s-75 .. 64s+75]  (64 + 87)
#define SC 36             // col stride in dwords (144 B, 16B-aligned, odd quad)
#define RED 23            // combine stride (23 coprime 32 -> 2-way alias = free)
#define REGION (64 * RED) // 1472 floats per wave's partial region
#define SMEMF (4 * REGION) // 5888 floats = 23552 B  (> NCOLS*SC = 5436)

// LDS: smem[col*SC + c] = feat_r[b, c, h, col + COL0], zero outside [0,W).
// After compute it is reused as the 4-region cross-wave reduction buffer.

__global__ __launch_bounds__(256, 4) void cost_volume_kernel(
    const float* __restrict__ feat_l,
    const float* __restrict__ feat_r,
    const float* __restrict__ disp,
    float* __restrict__ out)
{
    __shared__ __align__(16) float smem[SMEMF];   // 23552 B -> LDS not limiter

    const int t  = threadIdx.x;
    const int q  = t >> 6;          // wave id = channel octet (c0 = 8q)
    const int px = t & 63;          // pixel within segment
    const int s  = blockIdx.x >> 8; // grid = NSEG*256; siblings same XCD (256%8==0)
    const int bh = blockIdx.x & 255;
    const int b  = bh >> 7;
    const int h  = bh & 127;
    const int w  = s * SEG + px;
    const int COL0 = s * SEG - 75;
    const int c0 = q * 8;

    // ---- early independent global loads (overlap staging latency) ----
    float fl[8];
    const size_t lbase = ((size_t)(b * CC + c0)) * HW + (size_t)h * WW + w;
    #pragma unroll
    for (int k = 0; k < 8; ++k) fl[k] = feat_l[lbase + (size_t)k * HW];
    const float d = disp[(size_t)bh * WW + w];

    // ---- stage feat_r window, channel-interleaved, b128 LDS writes ----
    #pragma unroll
    for (int cc = 0; cc < 3; ++cc) {
        const int col = cc * 64 + px;
        if (col < NCOLS) {
            const int  gcol = col + COL0;
            const bool inr  = (gcol >= 0) && (gcol < WW);
            const int  gc   = min(max(gcol, 0), WW - 1);   // safe address
            #pragma unroll
            for (int qq = 0; qq < 2; ++qq) {
                const int cq = (q + 4 * qq) * 4;           // channel quad base
                const size_t base = ((size_t)(b * CC + cq)) * HW + (size_t)h * WW + gc;
                const float x0 = feat_r[base];
                const float x1 = feat_r[base + HW];
                const float x2 = feat_r[base + 2 * HW];
                const float x3 = feat_r[base + 3 * HW];
                float4 v;
                v.x = inr ? x0 : 0.0f;
                v.y = inr ? x1 : 0.0f;
                v.z = inr ? x2 : 0.0f;
                v.w = inr ? x3 : 0.0f;
                *(float4*)&smem[col * SC + cq] = v;
            }
        }
    }
    __syncthreads();

    // ---- per-pixel interp setup (shared across all di) ----
    const float pxf = (float)w - d;
    const float x0f = floorf(pxf);
    const float w1  = pxf - x0f;          // right-neighbor weight
    const float w0  = 1.0f - w1;
    int lb = (int)x0f - COL0 - 11;        // local col of tap j=0
    lb = min(max(lb, 0), NCOLS - 24);     // no-op for disp in [0,64)

    // ---- 24-tap window, prefetch distance 2, 8 channels per thread ----
    float4 Ta[3], Tb[3];
    #define LOADTAP(idx, j) { \
        const float4* p_ = (const float4*)&smem[(lb + (j)) * SC + c0]; \
        Ta[idx] = p_[0]; Tb[idx] = p_[1]; }

    LOADTAP(0, 0)
    LOADTAP(1, 1)

    float acc[DD];
    #pragma unroll
    for (int di = 0; di < DD; ++di) {
        if (di + 2 < 24) LOADTAP((di + 2) % 3, di + 2)
        const float4 A0 = Ta[di % 3],       A1 = Tb[di % 3];
        const float4 B0 = Ta[(di + 1) % 3], B1 = Tb[(di + 1) % 3];
        float sA = 0.0f, sB = 0.0f;
        sA += fabsf(fmaf(w0, A0.x, fmaf(w1, B0.x, -fl[0])));
        sB += fabsf(fmaf(w0, A0.y, fmaf(w1, B0.y, -fl[1])));
        sA += fabsf(fmaf(w0, A0.z, fmaf(w1, B0.z, -fl[2])));
        sB += fabsf(fmaf(w0, A0.w, fmaf(w1, B0.w, -fl[3])));
        sA += fabsf(fmaf(w0, A1.x, fmaf(w1, B1.x, -fl[4])));
        sB += fabsf(fmaf(w0, A1.y, fmaf(w1, B1.y, -fl[5])));
        sA += fabsf(fmaf(w0, A1.z, fmaf(w1, B1.z, -fl[6])));
        sB += fabsf(fmaf(w0, A1.w, fmaf(w1, B1.w, -fl[7])));
        acc[di] = sA + sB;
    }
    #undef LOADTAP

    // ---- balanced cross-wave combine: every wave publishes, every wave
    //      finalizes a di-range (own partial re-read from own region, so
    //      no runtime-indexed register array -> no scratch spill) ----
    __syncthreads();                       // all tap reads done before overwrite
    {
        float* r = &smem[q * REGION + px * RED];
        #pragma unroll
        for (int di = 0; di < DD; ++di) r[di] = acc[di];
    }
    __syncthreads();
    {
        const int R0 = q * 6;                      // wave q owns di in [R0, R0+L)
        const int L  = (q == 3) ? 5 : 6;
        const float* r0 = &smem[0 * REGION + px * RED];
        const float* r1 = r0 + REGION;
        const float* r2 = r0 + 2 * REGION;
        const float* r3 = r0 + 3 * REGION;
        #pragma unroll
        for (int di = 0; di < DD; ++di) {
            if (di >= R0 && di < R0 + L) {         // wave-uniform branch
                const float v = r0[di] + r1[di] + r2[di] + r3[di];
                out[((size_t)(b * DD + di)) * HW + (size_t)h * WW + w] = v;
            }
        }
    }
}

extern "C" void kernel_launch(void* const* d_in, const int* in_sizes, int n_in,
                              void* d_out, int out_size, void* d_ws, size_t ws_size,
                              hipStream_t stream)
{
    const float* feat_l = (const float*)d_in[0];
    const float* feat_r = (const float*)d_in[1];
    const float* disp   = (const float*)d_in[2];
    float* out = (float*)d_out;

    dim3 grid(NSEG * BB * HH);   // 1024 blocks: (wseg, b, h); 4 blocks/CU
    dim3 block(256);             // 4 waves: one channel-octet each
    cost_volume_kernel<<<grid, block, 0, stream>>>(feat_l, feat_r, disp, out);
}